// Round 13
// baseline (860.581 us; speedup 1.0000x reference)
//
#include <hip/hip_runtime.h>
#include <stdint.h>

// FUSED v3 (round 13 — first actual execution; r8-r11 were infra failures).
// Safety anchor: r12 re-verified the 705us split structure. v3's measured-analog
// downside is r6's 708 (fused v1); upside ~620-670 + resolves the LDS-residency
// question (occupancy pinned at 17.5% with 63KB LDS in r6 AND r7).
// v3: B (wfc) bypasses LDS entirely -> per-wave direct global->reg fragments
//     (wave wv owns n-tile wv; fragments byte-identical to what v1's LDS staging
//     delivered - re-verified vs the PASSING v1). LDS = A double-buffer only =
//     24KB -> clean test of the LDS-residency hypothesis.
//     Conv = v1 independent-slab scheme (measured faster than v2's carry).
//     Grid 512 = i(128) x g(4 row-groups of 50/50/50/47+pad rows), 384 thr.
//     Slab = 2 conv rows = 96 k = 3 MFMA k-steps; ONE lgkm-only barrier per slab.
//     Writes fp32 partials [g][b,i,n]; reduce kernel applies bias+sigmoid.
// Fallback: old round-1 fused kernel if ws too small for partials.

namespace {
constexpr int kB = 64, kI = 128, kN = 88, kT = 201, kF = 52;
constexpr int kT2 = 197, kF2 = 48;
constexpr int kFTOT = kT2 * kF2;  // 9456
constexpr int kTHREADS = 384;
constexpr int kOUT = kB * kI * kN;  // 720896
constexpr int kNCH = 12;   // A chunks of 8 bf16 per 96-k slab
constexpr int kNG = 4;     // row groups
// fallback fused kernel
constexpr int kNH = 44;
constexpr int kLDK = 200;
constexpr int kSLABS = 50;

typedef float f32x4 __attribute__((ext_vector_type(4)));
typedef __bf16 bf16x8 __attribute__((ext_vector_type(8)));
typedef unsigned short u16x8 __attribute__((ext_vector_type(8)));
typedef unsigned short u16x4 __attribute__((ext_vector_type(4)));

#define BAR_LGKM() asm volatile("s_waitcnt lgkmcnt(0)\n\ts_barrier" ::: "memory")

__device__ __forceinline__ unsigned short bf16_rne(float f) {
  unsigned int u = __float_as_uint(f);
  u += 0x7fffu + ((u >> 16) & 1u);
  return (unsigned short)(u >> 16);
}

__device__ __forceinline__ void loadrow(float* d, const float* p) {
  float4 a = *(const float4*)p;
  float4 b = *(const float4*)(p + 4);
  float4 c = *(const float4*)(p + 8);
  d[0] = a.x; d[1] = a.y; d[2] = a.z;  d[3] = a.w;
  d[4] = b.x; d[5] = b.y; d[6] = b.z;  d[7] = b.w;
  d[8] = c.x; d[9] = c.y; d[10] = c.z; d[11] = c.w;
}

__device__ __forceinline__ void c1row(float* o, const float* r0, const float* r1,
                                      const float* r2, const float* w, float bias) {
#pragma unroll
  for (int c = 0; c < 10; ++c) {
    float v = bias;
    v += r0[c] * w[0]; v += r0[c + 1] * w[1]; v += r0[c + 2] * w[2];
    v += r1[c] * w[3]; v += r1[c + 1] * w[4]; v += r1[c + 2] * w[5];
    v += r2[c] * w[6]; v += r2[c + 1] * w[7]; v += r2[c + 2] * w[8];
    o[c] = fmaxf(v, 0.0f);
  }
}

__device__ __forceinline__ u16x8 conv2row(const float* cx, const float* cy,
                                          const float* cz, const float* w2r,
                                          float b2r) {
  u16x8 o8;
#pragma unroll
  for (int c = 0; c < 8; ++c) {
    float v = b2r;
    v += cx[c] * w2r[0] + cx[c + 1] * w2r[1] + cx[c + 2] * w2r[2];
    v += cy[c] * w2r[3] + cy[c + 1] * w2r[4] + cy[c + 2] * w2r[5];
    v += cz[c] * w2r[6] + cz[c + 1] * w2r[7] + cz[c + 2] * w2r[8];
    o8[c] = bf16_rne(fmaxf(v, 0.0f));
  }
  return o8;
}
}  // namespace

// ---------------------------------------------------------------- fused3
__global__ __launch_bounds__(kTHREADS, 3) void fused3_kernel(
    const float* __restrict__ data, const float* __restrict__ w1,
    const float* __restrict__ b1, const float* __restrict__ w2,
    const float* __restrict__ b2, const float* __restrict__ wfc,
    float* __restrict__ partial) {
  // A: chunk-swizzled: chunk c holds k=c*8..+8 of 64 b-rows, slot=c*64+((b+c)&63).
  __shared__ unsigned short As[2][kNCH * 64 * 8];  // 2 x 12 KB = 24 KB total
  const int tid = threadIdx.x;
  const int i = blockIdx.x >> 2, g = blockIdx.x & 3;
  const int r0 = g * 50;                 // rows 0/50/100/150
  const int nslab = (g == 3) ? 24 : 25;  // rows 50/50/50/47(+1 pad)

  // conv role: thread (bb, oc) produces b-row bb, cols oc*8..+8
  const int bb = tid / 6, oc = tid - bb * 6;
  const float* dbase = data + bb * (kT * kF) + oc * 8;
  float w1r[9], w2r[9];
#pragma unroll
  for (int j = 0; j < 9; ++j) { w1r[j] = w1[i * 9 + j]; w2r[j] = w2[i * 9 + j]; }
  const float b1r = b1[i], b2r = b2[i];

  // MFMA role: wave wv owns n-tile wv (n = wv*16 + lc), all 4 m-tiles
  const int wv = tid >> 6, ln = tid & 63;
  const int lc = ln & 15, lq = ln >> 4;
  const int nB = wv * 16 + lc;           // 0..95; >=88 is pad
  const bool nOK = (nB < kN);
  const float* wrow = wfc + ((size_t)i * kN + (nOK ? nB : 0)) * kFTOT;

  f32x4 acc[4];
#pragma unroll
  for (int mt = 0; mt < 4; ++mt) acc[mt] = (f32x4){0.f, 0.f, 0.f, 0.f};

  for (int s = 0; s < nslab; ++s) {
    const int p = s & 1;
    const int t0 = r0 + 2 * s;
    const bool row1ok = (t0 + 1) < kT2;  // false only at g=3, s=23 (t0=196)

    // ---- conv input rows: all loads issued up front (MLP)
    float d0[12], d1[12], d2[12], d3[12], d4[12], d5[12];
    loadrow(d0, dbase + (t0 + 0) * kF);
    loadrow(d1, dbase + (t0 + 1) * kF);
    loadrow(d2, dbase + (t0 + 2) * kF);
    loadrow(d3, dbase + (t0 + 3) * kF);
    loadrow(d4, dbase + (t0 + 4) * kF);  // t0+4 <= 200 always
    if (row1ok) loadrow(d5, dbase + (t0 + 5) * kF);  // t0+5 <= 200 when ok

    // ---- B direct global->reg for this slab: n=nB, k = t0*48 + lq*8 + ks*32
    //      (in flight across the whole conv phase; cvt after the barrier)
    const int kb0 = t0 * kF2 + lq * 8;
    float4 bfr[6];
#pragma unroll
    for (int ks = 0; ks < 3; ++ks) {
      const int kk = kb0 + ks * 32;
      if (nOK && kk + 8 <= kFTOT) {   // tail-slab guard (g=3 only in practice)
        bfr[2 * ks]     = *(const float4*)(wrow + kk);
        bfr[2 * ks + 1] = *(const float4*)(wrow + kk + 4);
      } else {
        bfr[2 * ks]     = make_float4(0.f, 0.f, 0.f, 0.f);
        bfr[2 * ks + 1] = make_float4(0.f, 0.f, 0.f, 0.f);
      }
    }

    // ---- conv math -> A[p]
    {
      float c0[10], c1v[10], c2[10], c3[10];
      c1row(c0, d0, d1, d2, w1r, b1r);
      c1row(c1v, d1, d2, d3, w1r, b1r);
      c1row(c2, d2, d3, d4, w1r, b1r);
      u16x8 oA = conv2row(c0, c1v, c2, w2r, b2r);
      u16x8 oB;
      if (row1ok) {
        c1row(c3, d3, d4, d5, w1r, b1r);
        oB = conv2row(c1v, c2, c3, w2r, b2r);
      } else {
        u16x8 z = {0, 0, 0, 0, 0, 0, 0, 0};
        oB = z;  // pad row 197
      }
      const int cA = oc, cB = 6 + oc;  // chunk = (row-t0)*6 + oc
      *(u16x8*)(&As[p][(cA * 64 + ((bb + cA) & 63)) * 8]) = oA;
      *(u16x8*)(&As[p][(cB * 64 + ((bb + cB) & 63)) * 8]) = oB;
    }
    BAR_LGKM();  // lgkm drain + barrier; bfr global loads stay in flight

    // ---- cvt B in-reg + MFMA
    const unsigned short* Ap = As[p];
#pragma unroll
    for (int ks = 0; ks < 3; ++ks) {
      u16x8 t;
      t[0] = bf16_rne(bfr[2 * ks].x);     t[1] = bf16_rne(bfr[2 * ks].y);
      t[2] = bf16_rne(bfr[2 * ks].z);     t[3] = bf16_rne(bfr[2 * ks].w);
      t[4] = bf16_rne(bfr[2 * ks + 1].x); t[5] = bf16_rne(bfr[2 * ks + 1].y);
      t[6] = bf16_rne(bfr[2 * ks + 1].z); t[7] = bf16_rne(bfr[2 * ks + 1].w);
      bf16x8 bfrag = *(bf16x8*)&t;
      const int c = ks * 4 + lq;  // chunk holding k = ks*32 + lq*8
#pragma unroll
      for (int mt = 0; mt < 4; ++mt) {
        const int m = mt * 16 + lc;
        bf16x8 afrag = *(const bf16x8*)(Ap + (c * 64 + ((m + c) & 63)) * 8);
        acc[mt] = __builtin_amdgcn_mfma_f32_16x16x32_bf16(afrag, bfrag, acc[mt], 0, 0, 0);
      }
    }
    // single barrier/slab sound: wave writes A[p] again only at slab s+2, after
    // barrier s+1, by which time all waves' MFMA(s) ds_reads of A[p] drained.
  }

  // epilogue: C layout col(lane&15)=n, row=lq*4+r; fp32 partials
  float* dst = partial + (size_t)g * kOUT;
  if (nOK) {
#pragma unroll
    for (int mt = 0; mt < 4; ++mt) {
#pragma unroll
      for (int r = 0; r < 4; ++r) {
        const int b = mt * 16 + lq * 4 + r;
        dst[(size_t)(b * kI + i) * kN + nB] = acc[mt][r];
      }
    }
  }
}

// ---------------------------------------------------------------- reduce
__global__ __launch_bounds__(256) void reduce_sigmoid_kernel(
    const float* __restrict__ partial, const float* __restrict__ bfc,
    float* __restrict__ out) {
  const int idx = blockIdx.x * 256 + threadIdx.x;
  if (idx >= kOUT) return;
  const int n = idx % kN;
  const int i = (idx / kN) % kI;  // idx = (b*kI + i)*kN + n
  const float v = partial[idx] + partial[kOUT + idx] + partial[2 * kOUT + idx] +
                  partial[3 * kOUT + idx] + bfc[i * kN + n];
  out[idx] = 1.0f / (1.0f + __expf(-v));
}

// ------------------------------------------------- fallback: round-1 fused
__global__ __launch_bounds__(kTHREADS, 2) void fused_conv_fc_kernel(
    const float* __restrict__ data, const float* __restrict__ w1,
    const float* __restrict__ b1, const float* __restrict__ w2,
    const float* __restrict__ b2, const float* __restrict__ wfc,
    const float* __restrict__ bfc, float* __restrict__ out) {
  __shared__ unsigned short Ab[kB * kLDK];
  __shared__ unsigned short Bb[48 * kLDK];
  const int tid = threadIdx.x;
  const int i = blockIdx.x >> 1;
  const int nh = blockIdx.x & 1;
  const int nbase = nh * kNH;
  for (int z = tid; z < 4 * kLDK; z += kTHREADS) Bb[kNH * kLDK + z] = 0;
  float w1r[9], w2r[9];
#pragma unroll
  for (int j = 0; j < 9; ++j) { w1r[j] = w1[i * 9 + j]; w2r[j] = w2[i * 9 + j]; }
  const float b1r = b1[i], b2r = b2[i];
  const int bb = tid / 6;
  const int oc = tid - bb * 6;
  const int fr0 = oc * 8;
  const float* dbase = data + bb * (kT * kF) + fr0;
  float c1[6][10];
  float dA[12], dB[12], dC[12], dD[12];
  float4 W[6];
  loadrow(dC, dbase + 0 * kF);
  loadrow(dD, dbase + 1 * kF);
  loadrow(dA, dbase + 2 * kF);
  loadrow(dB, dbase + 3 * kF);
  c1row(c1[0], dC, dD, dA, w1r, b1r);
  c1row(c1[1], dD, dA, dB, w1r, b1r);
#pragma unroll
  for (int j = 0; j < 6; ++j) {
    int q = tid + kTHREADS * j;
    if (q < kNH * 48) {
      int n = q / 48, k4 = q - n * 48;
      W[j] = *(const float4*)(wfc + (size_t)(i * kN + nbase + n) * kFTOT + k4 * 4);
    } else {
      W[j] = make_float4(0.f, 0.f, 0.f, 0.f);
    }
  }
  const int wv = tid >> 6, ln = tid & 63;
  const int nt = wv % 3, mp = wv / 3;
  const int lc = ln & 15, lq = ln >> 4;
  f32x4 acc0 = {0.f, 0.f, 0.f, 0.f};
  f32x4 acc1 = {0.f, 0.f, 0.f, 0.f};
  for (int s = 0; s < kSLABS; ++s) {
    loadrow(dC, dbase + (4 * s + 4) * kF);
    c1row(c1[2], dA, dB, dC, w1r, b1r);
    if (s < kSLABS - 1) {
      loadrow(dD, dbase + (4 * s + 5) * kF);
      c1row(c1[3], dB, dC, dD, w1r, b1r);
      loadrow(dA, dbase + (4 * s + 6) * kF);
      c1row(c1[4], dC, dD, dA, w1r, b1r);
      loadrow(dB, dbase + (4 * s + 7) * kF);
      c1row(c1[5], dD, dA, dB, w1r, b1r);
    }
#pragma unroll
    for (int tl = 0; tl < 4; ++tl) {
      if (tl == 0 || s < kSLABS - 1) {
        u16x8 o8;
#pragma unroll
        for (int c = 0; c < 8; ++c) {
          float v = b2r;
#pragma unroll
          for (int r = 0; r < 3; ++r) {
            v += c1[tl + r][c] * w2r[3 * r];
            v += c1[tl + r][c + 1] * w2r[3 * r + 1];
            v += c1[tl + r][c + 2] * w2r[3 * r + 2];
          }
          o8[c] = bf16_rne(fmaxf(v, 0.0f));
        }
        *(u16x8*)&Ab[bb * kLDK + tl * 48 + fr0] = o8;
      }
    }
#pragma unroll
    for (int j = 0; j < 6; ++j) {
      int q = tid + kTHREADS * j;
      if (q < kNH * 48) {
        int n = q / 48, k4 = q - n * 48;
        u16x4 o;
        o[0] = bf16_rne(W[j].x); o[1] = bf16_rne(W[j].y);
        o[2] = bf16_rne(W[j].z); o[3] = bf16_rne(W[j].w);
        *(u16x4*)&Bb[n * kLDK + k4 * 4] = o;
      }
    }
    if (s + 1 < kSLABS) {
      const int real4 = (s + 1 == kSLABS - 1) ? 12 : 48;
#pragma unroll
      for (int j = 0; j < 6; ++j) {
        int q = tid + kTHREADS * j;
        int n = q / 48, k4 = q - n * 48;
        if (q < kNH * 48 && k4 < real4) {
          W[j] = *(const float4*)(wfc + (size_t)(i * kN + nbase + n) * kFTOT +
                                  (size_t)(s + 1) * 192 + k4 * 4);
        } else {
          W[j] = make_float4(0.f, 0.f, 0.f, 0.f);
        }
      }
    }
    __syncthreads();
    {
      const unsigned short* Ar0 = &Ab[(mp * 32 + lc) * kLDK];
      const unsigned short* Ar1 = Ar0 + 16 * kLDK;
      const unsigned short* Br = &Bb[(nt * 16 + lc) * kLDK];
      const int kq = lq * 8;
      const int kmax = (s != kSLABS - 1) ? 6 : 2;
      for (int ks = 0; ks < kmax; ++ks) {
        int ko = ks * 32 + kq;
        bf16x8 a0 = *(const bf16x8*)(Ar0 + ko);
        bf16x8 a1 = *(const bf16x8*)(Ar1 + ko);
        bf16x8 bfr = *(const bf16x8*)(Br + ko);
        acc0 = __builtin_amdgcn_mfma_f32_16x16x32_bf16(a0, bfr, acc0, 0, 0, 0);
        acc1 = __builtin_amdgcn_mfma_f32_16x16x32_bf16(a1, bfr, acc1, 0, 0, 0);
      }
    }
    __syncthreads();
    if (s < kSLABS - 1) {
#pragma unroll
      for (int c = 0; c < 10; ++c) { c1[0][c] = c1[4][c]; c1[1][c] = c1[5][c]; }
    }
  }
  const int nl = nt * 16 + lc;
  if (nl < kNH) {
    const int ng = nbase + nl;
    const float bias = bfc[i * kN + ng];
#pragma unroll
    for (int r = 0; r < 4; ++r) {
      int b0 = mp * 32 + lq * 4 + r;
      float v0 = acc0[r] + bias;
      out[(size_t)(b0 * kI + i) * kN + ng] = 1.0f / (1.0f + __expf(-v0));
      float v1 = acc1[r] + bias;
      out[(size_t)((b0 + 16) * kI + i) * kN + ng] = 1.0f / (1.0f + __expf(-v1));
    }
  }
}

extern "C" void kernel_launch(void* const* d_in, const int* in_sizes, int n_in,
                              void* d_out, int out_size, void* d_ws, size_t ws_size,
                              hipStream_t stream) {
  const float* data = (const float*)d_in[0];
  const float* w1 = (const float*)d_in[1];
  const float* b1 = (const float*)d_in[2];
  const float* w2 = (const float*)d_in[3];
  const float* b2 = (const float*)d_in[4];
  const float* wfc = (const float*)d_in[5];
  const float* bfc = (const float*)d_in[6];
  float* out = (float*)d_out;
  const size_t pb = (size_t)kOUT * 4;  // one partial slab: ~2.9 MB
  if (ws_size >= kNG * pb) {
    float* part = (float*)d_ws;
    fused3_kernel<<<dim3(kI * kNG), dim3(kTHREADS), 0, stream>>>(
        data, w1, b1, w2, b2, wfc, part);
    reduce_sigmoid_kernel<<<dim3((kOUT + 255) / 256), dim3(256), 0, stream>>>(
        part, bfc, out);
  } else {
    fused_conv_fc_kernel<<<dim3(kI * 2), dim3(kTHREADS), 0, stream>>>(
        data, w1, b1, w2, b2, wfc, bfc, out);
  }
}